// Round 2
// baseline (223.525 us; speedup 1.0000x reference)
//
#include <hip/hip_runtime.h>

#define CIN  32
#define COUT 64
#define PP   1024
#define NN   24
#define NA   60
#define KS   4
#define PA   (PP*NA)          // 61440
#define CK   (CIN*KS)         // 128
#define NAK  (NA*KS)          // 240
constexpr float SIGMA_INV = 12.5f;   // 1/0.08
constexpr float EPS = 1e-5f;

// ---------------- k1: fused conv + GEMM + partial sums ----------------
__global__ __launch_bounds__(256) void k1_fused(
    const float* __restrict__ xyz,       // [3,P]
    const float* __restrict__ feats,     // [CIN,P,NA]
    const int*   __restrict__ inter_idx, // [P,NN]
    const float* __restrict__ anchors,   // [NA,3,3]
    const float* __restrict__ kern,      // [KS,3]
    const float* __restrict__ Wf,        // [COUT,CK]
    float* __restrict__ out_pre,         // [COUT,P,NA]  (= d_out, pre-norm)
    float* __restrict__ psum,            // [COUT,P]
    float* __restrict__ psq)             // [COUT,P]
{
    const int p   = blockIdx.x;
    const int tid = threadIdx.x;
    const int g   = tid >> 6;   // wave id 0..3
    const int l   = tid & 63;   // lane

    __shared__ float s_relx[NN], s_rely[NN], s_relz[NN], s_r2[NN];
    __shared__ float s_rkx[NAK], s_rky[NAK], s_rkz[NAK], s_rk2[NAK];
    __shared__ float s_w[NN*NA*KS];    // [n][a][k] -> contiguous k for b128 reads
    __shared__ float s_fk[CK*NA];      // [c*4+k][a]
    __shared__ int   s_idx[NN];

    // --- phase A: neighbor relative coords ---
    if (tid < NN) {
        int j = inter_idx[p*NN + tid];
        s_idx[tid] = j;
        float rx = xyz[j]        - xyz[p];
        float ry = xyz[PP + j]   - xyz[PP + p];
        float rz = xyz[2*PP + j] - xyz[2*PP + p];
        s_relx[tid] = rx; s_rely[tid] = ry; s_relz[tid] = rz;
        s_r2[tid] = rx*rx + ry*ry + rz*rz;
    }
    // --- phase B: anchor-rotated kernel points rk[a,k,:] ---
    if (tid < NAK) {
        int a = tid >> 2, k = tid & 3;
        float kx = kern[k*3+0];
        float ky = kern[k*3+1];
        float kz = kern[k*3+2];
        const float* A = anchors + a*9;
        float r0 = A[0]*kx + A[1]*ky + A[2]*kz;
        float r1 = A[3]*kx + A[4]*ky + A[5]*kz;
        float r2 = A[6]*kx + A[7]*ky + A[8]*kz;
        s_rkx[tid] = r0; s_rky[tid] = r1; s_rkz[tid] = r2;
        s_rk2[tid] = r0*r0 + r1*r1 + r2*r2;
    }
    __syncthreads();

    // --- phase C: w[n][a][k] = relu(1 - d2/sigma) ---
    for (int t = tid; t < NN*NA*KS; t += 256) {
        int k  = t & 3;
        int na = t >> 2;
        int a  = na % NA;
        int n  = na / NA;
        int ak = a*4 + k;
        float d2 = s_r2[n] + s_rk2[ak]
                 - 2.0f*(s_relx[n]*s_rkx[ak] + s_rely[n]*s_rky[ak] + s_relz[n]*s_rkz[ak]);
        float wv = 1.0f - d2 * SIGMA_INV;
        s_w[t] = wv > 0.0f ? wv : 0.0f;
    }
    __syncthreads();

    // --- phase D: fk[c,k,a] = sum_n feats[c, idx[n], a] * w[n,a,k] ---
    const bool valid = (l < NA);
    const int  a     = valid ? l : (NA - 1);   // clamped so all lanes stay convergent

    for (int cc = 0; cc < CIN/4; ++cc) {
        int c = g*(CIN/4) + cc;                 // 8 channels per wave
        const float* fb = feats + (size_t)c*PA + a;
        float a0 = 0.f, a1 = 0.f, a2 = 0.f, a3 = 0.f;
        #pragma unroll
        for (int n = 0; n < NN; ++n) {
            float f = fb[s_idx[n]*NA];
            const float* wp = &s_w[(n*NA + a)*4];   // 16B aligned -> ds_read_b128
            a0 += f*wp[0]; a1 += f*wp[1]; a2 += f*wp[2]; a3 += f*wp[3];
        }
        if (valid) {
            int c4 = c*4;
            s_fk[(c4+0)*NA + a] = a0;
            s_fk[(c4+1)*NA + a] = a1;
            s_fk[(c4+2)*NA + a] = a2;
            s_fk[(c4+3)*NA + a] = a3;
        }
    }
    __syncthreads();

    // --- phase E: out[d,a] = sum_ck W[d,ck]*fk[ck,a]; 16 d per thread ---
    float acc[16];
    #pragma unroll
    for (int j = 0; j < 16; ++j) acc[j] = 0.f;

    for (int ck = 0; ck < CK; ++ck) {
        float fv = s_fk[ck*NA + a];
        #pragma unroll
        for (int j = 0; j < 16; ++j)
            acc[j] += Wf[(g*16 + j)*CK + ck] * fv;   // wave-uniform -> scalar loads
    }

    // --- store pre-norm output + per-(p,d) partial sums via wave shuffles ---
    const size_t obase = (size_t)p*NA + a;
    #pragma unroll
    for (int j = 0; j < 16; ++j) {
        int d = g*16 + j;
        float v = valid ? acc[j] : 0.0f;
        if (valid) out_pre[(size_t)d*PA + obase] = v;
        float s = v, q = v*v;
        #pragma unroll
        for (int off = 32; off; off >>= 1) {
            s += __shfl_down(s, off, 64);
            q += __shfl_down(q, off, 64);
        }
        if (l == 0) {
            psum[d*PP + p] = s;
            psq [d*PP + p] = q;
        }
    }
}

// ---------------- k2: per-channel mean / rsqrt(var) ----------------
__global__ __launch_bounds__(256) void k2_stats(
    const float* __restrict__ psum, const float* __restrict__ psq,
    float* __restrict__ stats)
{
    int d = blockIdx.x, tid = threadIdx.x;
    float s = 0.f, q = 0.f;
    for (int t = tid; t < PP; t += 256) {
        s += psum[d*PP + t];
        q += psq [d*PP + t];
    }
    #pragma unroll
    for (int off = 32; off; off >>= 1) {
        s += __shfl_down(s, off, 64);
        q += __shfl_down(q, off, 64);
    }
    __shared__ float ss[4], sq[4];
    int w = tid >> 6;
    if ((tid & 63) == 0) { ss[w] = s; sq[w] = q; }
    __syncthreads();
    if (tid == 0) {
        float S = ss[0]+ss[1]+ss[2]+ss[3];
        float Q = sq[0]+sq[1]+sq[2]+sq[3];
        const float inv = 1.0f / (float)PA;
        float mu  = S * inv;
        float var = Q * inv - mu*mu;
        stats[d]        = mu;
        stats[COUT + d] = rsqrtf(var + EPS);
    }
}

// ---------------- k3: normalize + relu in place ----------------
__global__ __launch_bounds__(256) void k3_norm(
    float* __restrict__ out, const float* __restrict__ stats)
{
    int d = blockIdx.y;
    int i = blockIdx.x * 256 + threadIdx.x;     // 0..PA-1
    float mu = stats[d], rs = stats[COUT + d];
    size_t o = (size_t)d*PA + i;
    float v = (out[o] - mu) * rs;
    out[o] = v > 0.f ? v : 0.f;
}

extern "C" void kernel_launch(void* const* d_in, const int* in_sizes, int n_in,
                              void* d_out, int out_size, void* d_ws, size_t ws_size,
                              hipStream_t stream) {
    const float* xyz     = (const float*)d_in[0];
    const float* feats   = (const float*)d_in[1];
    const int*   idx     = (const int*)d_in[2];
    const float* anchors = (const float*)d_in[3];
    const float* kern    = (const float*)d_in[4];
    const float* W       = (const float*)d_in[5];
    float* out = (float*)d_out;

    float* ws    = (float*)d_ws;
    float* psum  = ws;                 // 65,536 floats
    float* psq   = psum + COUT*PP;     // 65,536 floats
    float* stats = psq  + COUT*PP;     // 128 floats

    hipLaunchKernelGGL(k1_fused, dim3(PP), dim3(256), 0, stream,
                       xyz, feats, idx, anchors, kern, W, out, psum, psq);
    hipLaunchKernelGGL(k2_stats, dim3(COUT), dim3(256), 0, stream, psum, psq, stats);
    hipLaunchKernelGGL(k3_norm, dim3(PA/256, COUT), dim3(256), 0, stream, out, stats);
}

// Round 3
// 145.562 us; speedup vs baseline: 1.5356x; 1.5356x over previous
//
#include <hip/hip_runtime.h>

#define CIN  32
#define COUT 64
#define PP   1024
#define NN   24
#define NA   60
#define KS   4
#define PA   (PP*NA)          // 61440
#define CK   (CIN*KS)         // 128
constexpr float SIGMA_INV = 12.5f;   // 1/0.08
constexpr float EPS = 1e-5f;

// ---------------- k0: transpose feats [CIN,P,NA] -> ft [P,NA,CIN] ----------------
__global__ __launch_bounds__(256) void k0_transpose(
    const float* __restrict__ feats, float* __restrict__ ft)
{
    int p = blockIdx.x;
    for (int i = threadIdx.x; i < CIN*NA; i += 256) {
        int c = i / NA, a = i - c*NA;
        ft[((size_t)p*NA + a)*CIN + c] = feats[(size_t)c*PA + (size_t)p*NA + a];
    }
}

// ---------------- k1: fused conv + GEMM + partial sums ----------------
__global__ __launch_bounds__(256) void k1_fused(
    const float* __restrict__ xyz,       // [3,P]
    const float* __restrict__ ft,        // [P,NA,CIN]
    const int*   __restrict__ inter_idx, // [P,NN]
    const float* __restrict__ anchors,   // [NA,3,3]
    const float* __restrict__ kern,      // [KS,3]
    const float* __restrict__ Wf,        // [COUT,CK]
    float* __restrict__ out_pre,         // [COUT,P,NA]
    float* __restrict__ psum,            // [COUT,P]
    float* __restrict__ psq)             // [COUT,P]
{
    const int p   = blockIdx.x;
    const int tid = threadIdx.x;
    const int g   = tid >> 6;
    const int l   = tid & 63;
    const bool valid = (l < NA);
    const int  a     = valid ? l : (NA - 1);

    __shared__ float4 s_rel[NN];
    __shared__ int    s_idx[NN];
    __shared__ float  s_fk[CK*NA];       // [ck][a], 30.7 KB

    // --- phase A: neighbor relative coords (24 threads) ---
    if (tid < NN) {
        int j = inter_idx[p*NN + tid];
        s_idx[tid] = j;
        float rx = xyz[j]        - xyz[p];
        float ry = xyz[PP + j]   - xyz[PP + p];
        float rz = xyz[2*PP + j] - xyz[2*PP + p];
        s_rel[tid] = make_float4(rx, ry, rz, rx*rx + ry*ry + rz*rz);
    }

    // --- phase B: per-thread rotated-kernel constants for its anchor a ---
    float Cw[KS], Rx[KS], Ry[KS], Rz[KS];
    {
        const float* A = anchors + a*9;
        float a00=A[0],a01=A[1],a02=A[2],a10=A[3],a11=A[4],a12=A[5],a20=A[6],a21=A[7],a22=A[8];
        #pragma unroll
        for (int k = 0; k < KS; ++k) {
            float kx = kern[k*3+0], ky = kern[k*3+1], kz = kern[k*3+2];
            float r0 = a00*kx + a01*ky + a02*kz;
            float r1 = a10*kx + a11*ky + a12*kz;
            float r2 = a20*kx + a21*ky + a22*kz;
            Cw[k] = 1.0f - SIGMA_INV*(r0*r0 + r1*r1 + r2*r2);
            Rx[k] = 2.0f*SIGMA_INV*r0;
            Ry[k] = 2.0f*SIGMA_INV*r1;
            Rz[k] = 2.0f*SIGMA_INV*r2;
        }
    }
    __syncthreads();

    // --- phase D: fk[c,k] accumulation with on-the-fly weights ---
    float acc[8][KS];
    #pragma unroll
    for (int c = 0; c < 8; ++c)
        #pragma unroll
        for (int k = 0; k < KS; ++k) acc[c][k] = 0.0f;

    #pragma unroll
    for (int n = 0; n < NN; ++n) {
        float4 rel = s_rel[n];
        int j = s_idx[n];
        const float* fp = ft + ((size_t)j*NA + a)*CIN + g*8;
        float4 f0 = *(const float4*)(fp);
        float4 f1 = *(const float4*)(fp + 4);
        float tb = -SIGMA_INV * rel.w;
        float w[KS];
        #pragma unroll
        for (int k = 0; k < KS; ++k) {
            float v = Cw[k] + tb;
            v = fmaf(rel.x, Rx[k], v);
            v = fmaf(rel.y, Ry[k], v);
            v = fmaf(rel.z, Rz[k], v);
            w[k] = v > 0.0f ? v : 0.0f;
        }
        float f[8] = {f0.x,f0.y,f0.z,f0.w,f1.x,f1.y,f1.z,f1.w};
        #pragma unroll
        for (int c = 0; c < 8; ++c)
            #pragma unroll
            for (int k = 0; k < KS; ++k)
                acc[c][k] = fmaf(f[c], w[k], acc[c][k]);
    }

    if (valid) {
        #pragma unroll
        for (int c = 0; c < 8; ++c)
            #pragma unroll
            for (int k = 0; k < KS; ++k)
                s_fk[((g*8 + c)*KS + k)*NA + a] = acc[c][k];  // consecutive lanes -> consecutive addr
    }
    __syncthreads();

    // --- phase E: out[d,a] = sum_ck W[d,ck]*fk[ck,a]; W via scalar loads ---
    float accE[16];
    #pragma unroll
    for (int j = 0; j < 16; ++j) accE[j] = 0.0f;

    const int d0 = __builtin_amdgcn_readfirstlane(g * 16);   // wave-uniform -> s_load path
    const float* Wrow = Wf + (size_t)d0 * CK;

    #pragma unroll 4
    for (int ck = 0; ck < CK; ++ck) {
        float fv = s_fk[ck*NA + a];
        #pragma unroll
        for (int j = 0; j < 16; ++j)
            accE[j] = fmaf(Wrow[(size_t)j*CK + ck], fv, accE[j]);
    }

    // --- store pre-norm output + per-(p,d) partial sums via wave shuffles ---
    const size_t obase = (size_t)p*NA + a;
    #pragma unroll
    for (int j = 0; j < 16; ++j) {
        int d = d0 + j;
        float v = valid ? accE[j] : 0.0f;
        if (valid) out_pre[(size_t)d*PA + obase] = v;
        float s = v, q = v*v;
        #pragma unroll
        for (int off = 32; off; off >>= 1) {
            s += __shfl_down(s, off, 64);
            q += __shfl_down(q, off, 64);
        }
        if (l == 0) {
            psum[d*PP + p] = s;
            psq [d*PP + p] = q;
        }
    }
}

// ---------------- k2: per-channel mean / rsqrt(var) ----------------
__global__ __launch_bounds__(256) void k2_stats(
    const float* __restrict__ psum, const float* __restrict__ psq,
    float* __restrict__ stats)
{
    int d = blockIdx.x, tid = threadIdx.x;
    float s = 0.f, q = 0.f;
    for (int t = tid; t < PP; t += 256) {
        s += psum[d*PP + t];
        q += psq [d*PP + t];
    }
    #pragma unroll
    for (int off = 32; off; off >>= 1) {
        s += __shfl_down(s, off, 64);
        q += __shfl_down(q, off, 64);
    }
    __shared__ float ss[4], sq[4];
    int w = tid >> 6;
    if ((tid & 63) == 0) { ss[w] = s; sq[w] = q; }
    __syncthreads();
    if (tid == 0) {
        float S = ss[0]+ss[1]+ss[2]+ss[3];
        float Q = sq[0]+sq[1]+sq[2]+sq[3];
        const float inv = 1.0f / (float)PA;
        float mu  = S * inv;
        float var = Q * inv - mu*mu;
        stats[d]        = mu;
        stats[COUT + d] = rsqrtf(var + EPS);
    }
}

// ---------------- k3: normalize + relu in place (float4) ----------------
__global__ __launch_bounds__(256) void k3_norm(
    float* __restrict__ out, const float* __restrict__ stats)
{
    int d = blockIdx.y;
    int i = (blockIdx.x * 256 + threadIdx.x) * 4;   // 0..PA-1, PA % 1024 == 0
    float mu = stats[d], rs = stats[COUT + d];
    float4* po = (float4*)(out + (size_t)d*PA + i);
    float4 v = *po;
    v.x = fmaxf((v.x - mu)*rs, 0.f);
    v.y = fmaxf((v.y - mu)*rs, 0.f);
    v.z = fmaxf((v.z - mu)*rs, 0.f);
    v.w = fmaxf((v.w - mu)*rs, 0.f);
    *po = v;
}

extern "C" void kernel_launch(void* const* d_in, const int* in_sizes, int n_in,
                              void* d_out, int out_size, void* d_ws, size_t ws_size,
                              hipStream_t stream) {
    const float* xyz     = (const float*)d_in[0];
    const float* feats   = (const float*)d_in[1];
    const int*   idx     = (const int*)d_in[2];
    const float* anchors = (const float*)d_in[3];
    const float* kern    = (const float*)d_in[4];
    const float* W       = (const float*)d_in[5];
    float* out = (float*)d_out;

    float* ws    = (float*)d_ws;
    float* ft    = ws;                           // P*NA*CIN = 1,966,080 floats
    float* psum  = ft + (size_t)PP*NA*CIN;       // 65,536
    float* psq   = psum + COUT*PP;               // 65,536
    float* stats = psq  + COUT*PP;               // 128

    hipLaunchKernelGGL(k0_transpose, dim3(PP), dim3(256), 0, stream, feats, ft);
    hipLaunchKernelGGL(k1_fused, dim3(PP), dim3(256), 0, stream,
                       xyz, ft, idx, anchors, kern, W, out, psum, psq);
    hipLaunchKernelGGL(k2_stats, dim3(COUT), dim3(256), 0, stream, psum, psq, stats);
    hipLaunchKernelGGL(k3_norm, dim3(PA/1024, COUT), dim3(256), 0, stream, out, stats);
}